// Round 18
// baseline (78.809 us; speedup 1.0000x reference)
//
#include <hip/hip_runtime.h>
#include <hip/hip_fp16.h>

#define IMG_H 1024
#define IMG_W 1024
#define NIMG  16
#define RAD   5
#define KW    11
#define TX    64              // block tile width (cols); 16 per wave
#define WTX   16              // cols per wave
#define STRIP 128             // tile height (rows per block)
#define ASTEP 16              // h-blur rows per A step
#define BSTEP 32              // output rows per B step
#define HBROWS (STRIP + 2*RAD)   // 138 h-blurred rows per strip
#define RING  48              // ring rows per wave
#define WPAD  20              // halfs per hb ring row (16 + 4 pad)
#define RPAD  36              // halfs per raw-stage row (32 + 4 pad)
#define NQ    4               // ring quantities: x, y, xx+yy, xy
#define NPIX  (NIMG * IMG_H * IMG_W)

// Gaussian(sigma=1.5, 11 taps), normalized fp32 — matches reference window.
__device__ __forceinline__ float gw(int k) {
    constexpr float G[KW] = {
        0.00102838f, 0.00759876f, 0.03600077f, 0.10936070f, 0.21300554f,
        0.26601173f,
        0.21300554f, 0.10936070f, 0.03600077f, 0.00759876f, 0.00102838f};
    return G[k];
}

__device__ __forceinline__ unsigned h2u(__half2 v) {
    union { __half2 h; unsigned u; } c; c.h = v; return c.u;
}
__device__ __forceinline__ __half2 u2h(unsigned v) {
    union { unsigned u; __half2 h; } c; c.u = v; return c.h;
}
// halfs (w[idx], w[idx+1]) from packed word array; odd idx = v_alignbit.
__device__ __forceinline__ __half2 hsel(const unsigned* hw, int idx) {
    unsigned r;
    if (idx & 1) r = (hw[idx >> 1] >> 16) | (hw[(idx >> 1) + 1] << 16);
    else         r = hw[idx >> 1];
    return u2h(r);
}

// R17 (67.7us: wave-private rings, barrier-free) + raw-pixel staging:
// each thread loads only ITS 8 halo-cols (4 float4 vs 10) and converts once
// (8 cvt_pk vs 20); windows are read back from a wave-private LDS stage
// (conflict-free b64, 36-half stride). Kills the 4.3x L1 amplification of
// register-private windows. Wave-synchronous write->read: no barrier.
__global__ __launch_bounds__(256, 8) void ssim_strip_kernel(
        const float* __restrict__ img1, const float* __restrict__ img2,
        float* __restrict__ partial, int atomic_mode) {
    __shared__ __align__(16) __half hb[4][NQ][RING][WPAD];    // 30,720 B
    __shared__ __align__(16) __half rawst[4][2][ASTEP][RPAD]; //  9,216 B
    __shared__ float wsum[4];

    const int t = threadIdx.x;
    const int wid = t >> 6;
    const int lane = t & 63;
    const int tile_y = blockIdx.y * STRIP;
    const int wx = blockIdx.x * TX + wid * WTX;   // wave's first output col
    const size_t img_off = (size_t)blockIdx.z * (IMG_H * IMG_W);
    const float* p1 = img1 + img_off;
    const float* p2 = img2 + img_off;

    const bool x_ok = (wx >= 8) && (wx + 24 <= IMG_W);

    // Phase A step a: stage 8 own cols -> LDS, read 20-half window back,
    // h-blur 4 cols x 4 quantities into the wave's hb ring (slot h%48).
    auto phaseA = [&](int a) {
        const int lr = lane >> 2;
        const int g4 = lane & 3;
        const int h = ASTEP * a + lr;
        if (h >= HBROWS) return;
        int rr = h;
        if (rr >= 96) rr -= 96;
        else if (rr >= RING) rr -= RING;
        const int gr = tile_y + h - RAD;
        const int gcs = wx - 8 + g4 * 8;   // first of this thread's 8 cols
        const bool row_ok = (tile_y + ASTEP * a - RAD >= 0) &&
                            (tile_y + ASTEP * a + ASTEP - 1 - RAD < IMG_H);

        // ---- stage: load own 8 cols of both images, cvt, write to LDS ----
        uint2 w0, w1, v0, v1;
        if (x_ok && row_ok) {
            const size_t base = (size_t)gr * IMG_W + gcs;
            const float4 xa = *reinterpret_cast<const float4*>(p1 + base);
            const float4 xb = *reinterpret_cast<const float4*>(p1 + base + 4);
            const float4 ya = *reinterpret_cast<const float4*>(p2 + base);
            const float4 yb = *reinterpret_cast<const float4*>(p2 + base + 4);
            w0 = make_uint2(h2u(__floats2half2_rn(xa.x, xa.y)),
                            h2u(__floats2half2_rn(xa.z, xa.w)));
            w1 = make_uint2(h2u(__floats2half2_rn(xb.x, xb.y)),
                            h2u(__floats2half2_rn(xb.z, xb.w)));
            v0 = make_uint2(h2u(__floats2half2_rn(ya.x, ya.y)),
                            h2u(__floats2half2_rn(ya.z, ya.w)));
            v1 = make_uint2(h2u(__floats2half2_rn(yb.x, yb.y)),
                            h2u(__floats2half2_rn(yb.z, yb.w)));
        } else {
            const bool rowok = ((unsigned)gr < (unsigned)IMG_H);
            const float* r1 = p1 + (size_t)gr * IMG_W;
            const float* r2 = p2 + (size_t)gr * IMG_W;
            float fx[8], fy[8];
#pragma unroll
            for (int j = 0; j < 8; ++j) {
                const int g = gcs + j;
                const bool ok = rowok && ((unsigned)g < (unsigned)IMG_W);
                fx[j] = ok ? r1[g] : 0.f;
                fy[j] = ok ? r2[g] : 0.f;
            }
            w0 = make_uint2(h2u(__floats2half2_rn(fx[0], fx[1])),
                            h2u(__floats2half2_rn(fx[2], fx[3])));
            w1 = make_uint2(h2u(__floats2half2_rn(fx[4], fx[5])),
                            h2u(__floats2half2_rn(fx[6], fx[7])));
            v0 = make_uint2(h2u(__floats2half2_rn(fy[0], fy[1])),
                            h2u(__floats2half2_rn(fy[2], fy[3])));
            v1 = make_uint2(h2u(__floats2half2_rn(fy[4], fy[5])),
                            h2u(__floats2half2_rn(fy[6], fy[7])));
        }
        *reinterpret_cast<uint2*>(&rawst[wid][0][lr][g4 * 8])     = w0;
        *reinterpret_cast<uint2*>(&rawst[wid][0][lr][g4 * 8 + 4]) = w1;
        *reinterpret_cast<uint2*>(&rawst[wid][1][lr][g4 * 8])     = v0;
        *reinterpret_cast<uint2*>(&rawst[wid][1][lr][g4 * 8 + 4]) = v1;

        // ---- window read-back (wave-synchronous; conflict-free b64) ----
        unsigned hwx[10], hwy[10];
        const int wb = g4 * 4;   // window start half (8B aligned)
#pragma unroll
        for (int j = 0; j < 5; ++j) {
            const uint2 a2 =
                *reinterpret_cast<const uint2*>(&rawst[wid][0][lr][wb + 4 * j]);
            hwx[2 * j] = a2.x;
            hwx[2 * j + 1] = a2.y;
            const uint2 b2 =
                *reinterpret_cast<const uint2*>(&rawst[wid][1][lr][wb + 4 * j]);
            hwy[2 * j] = b2.x;
            hwy[2 * j + 1] = b2.y;
        }

        // ---- packed-fp16 h-blur: 4 cols = 2 half2 lanes x 4 quantities ----
        __half2 A0[2], A1[2], A2[2], A3[2];
#pragma unroll
        for (int p = 0; p < 2; ++p)
            A0[p] = A1[p] = A2[p] = A3[p] = u2h(0u);
#pragma unroll
        for (int k = 0; k < KW; ++k) {
            const __half2 g2 = __float2half2_rn(gw(k));
#pragma unroll
            for (int p = 0; p < 2; ++p) {
                const int idx = 2 * p + 3 + k;
                const __half2 X = hsel(hwx, idx);
                const __half2 Y = hsel(hwy, idx);
                A0[p] = __hfma2(g2, X, A0[p]);
                A1[p] = __hfma2(g2, Y, A1[p]);
                const __half2 gx = __hmul2(g2, X);
                const __half2 gy = __hmul2(g2, Y);
                A2[p] = __hfma2(gx, X, A2[p]);
                A2[p] = __hfma2(gy, Y, A2[p]);
                A3[p] = __hfma2(gx, Y, A3[p]);
            }
        }
        *reinterpret_cast<uint2*>(&hb[wid][0][rr][g4 * 4]) = make_uint2(h2u(A0[0]), h2u(A0[1]));
        *reinterpret_cast<uint2*>(&hb[wid][1][rr][g4 * 4]) = make_uint2(h2u(A1[0]), h2u(A1[1]));
        *reinterpret_cast<uint2*>(&hb[wid][2][rr][g4 * 4]) = make_uint2(h2u(A2[0]), h2u(A2[1]));
        *reinterpret_cast<uint2*>(&hb[wid][3][rr][g4 * 4]) = make_uint2(h2u(A3[0]), h2u(A3[1]));
    };

    float lsum = 0.f;

    // Phase B step s: v-blur + SSIM for output rows 32s..32s+31.
    // lane: 4 cols (slot = lane&3) x 2 rows (r2 = (lane>>2)*2).
    auto phaseB = [&](int s) {
        __half2 gh2[KW];
#pragma unroll
        for (int k = 0; k < KW; ++k) gh2[k] = __float2half2_rn(gw(k));

        const int rbase = (BSTEP * s) % RING;   // 0,32,16,0
        const int slot = lane & 3;
        const int r2 = (lane >> 2) * 2;
        __half2 acc[NQ][2][2];
#pragma unroll
        for (int q = 0; q < NQ; ++q)
#pragma unroll
            for (int rl = 0; rl < 2; ++rl)
#pragma unroll
                for (int cp = 0; cp < 2; ++cp)
                    acc[q][rl][cp] = u2h(0u);

#pragma unroll
        for (int q = 0; q < NQ; ++q) {
#pragma unroll
            for (int k = 0; k < KW + 1; ++k) {
                int r = rbase + r2 + k;
                if (r >= RING) r -= RING;
                const uint2 rv =
                    *reinterpret_cast<const uint2*>(&hb[wid][q][r][slot * 4]);
                __half2 h0 = u2h(rv.x);
                __half2 h1 = u2h(rv.y);
                if (k < KW) {
                    acc[q][0][0] = __hfma2(gh2[k], h0, acc[q][0][0]);
                    acc[q][0][1] = __hfma2(gh2[k], h1, acc[q][0][1]);
                }
                if (k > 0) {
                    acc[q][1][0] = __hfma2(gh2[k - 1], h0, acc[q][1][0]);
                    acc[q][1][1] = __hfma2(gh2[k - 1], h1, acc[q][1][1]);
                }
            }
        }

        const float C1 = 0.0001f;
        const float C2 = 0.0009f;
#pragma unroll
        for (int rl = 0; rl < 2; ++rl) {
#pragma unroll
            for (int cp = 0; cp < 2; ++cp) {
                float2 m1p = __half22float2(acc[0][rl][cp]);
                float2 m2p = __half22float2(acc[1][rl][cp]);
                float2 Sp  = __half22float2(acc[2][rl][cp]);   // blur(xx+yy)
                float2 Pp  = __half22float2(acc[3][rl][cp]);   // blur(xy)
#pragma unroll
                for (int e = 0; e < 2; ++e) {
                    float m1 = e ? m1p.y : m1p.x;
                    float m2 = e ? m2p.y : m2p.x;
                    float S  = e ? Sp.y  : Sp.x;
                    float P  = e ? Pp.y  : Pp.x;
                    float m1s = m1 * m1;
                    float m2s = m2 * m2;
                    float m12 = m1 * m2;
                    float sigsum = S - m1s - m2s;
                    float sig12  = P - m12;
                    float num = (2.f * m12 + C1) * (2.f * sig12 + C2);
                    float den = (m1s + m2s + C1) * (sigsum + C2);
                    lsum = fmaf(num, __builtin_amdgcn_rcpf(den), lsum);
                }
            }
        }
    };

    // Barrier-free per-wave schedule (ring safety: program order per wave;
    // raw stage rows are overwritten only by the same wave's next A-step,
    // after its own reads — in-order LDS per wave guarantees safety).
#pragma unroll 1
    for (int a = 0; a < 9; ++a) {
        phaseA(a);
        if (a >= 2 && ((a & 1) == 0)) {
            phaseB((a - 2) >> 1);
        }
    }

    // ---- block reduction (single barrier of the kernel) ----
#pragma unroll
    for (int off = 32; off > 0; off >>= 1)
        lsum += __shfl_down(lsum, off, 64);
    if (lane == 0) wsum[wid] = lsum;
    __syncthreads();
    if (t == 0) {
        float s = wsum[0] + wsum[1] + wsum[2] + wsum[3];
        if (atomic_mode) {
            atomicAdd(partial, s);
        } else {
            int bid = (blockIdx.z * gridDim.y + blockIdx.y) * gridDim.x + blockIdx.x;
            partial[bid] = s;
        }
    }
}

__global__ __launch_bounds__(256) void ssim_reduce_kernel(
        const float* __restrict__ partial, int n, float* __restrict__ out) {
    float s = 0.f;
    for (int i = threadIdx.x; i < n; i += 256) s += partial[i];
#pragma unroll
    for (int off = 32; off > 0; off >>= 1)
        s += __shfl_down(s, off, 64);
    __shared__ float ws[4];
    if ((threadIdx.x & 63) == 0) ws[threadIdx.x >> 6] = s;
    __syncthreads();
    if (threadIdx.x == 0) {
        float tot = ws[0] + ws[1] + ws[2] + ws[3];
        out[0] = 1.f - tot / (float)NPIX;
    }
}

extern "C" void kernel_launch(void* const* d_in, const int* in_sizes, int n_in,
                              void* d_out, int out_size, void* d_ws, size_t ws_size,
                              hipStream_t stream) {
    const float* img1 = (const float*)d_in[0];
    const float* img2 = (const float*)d_in[1];
    float* out = (float*)d_out;
    float* partial = (float*)d_ws;

    dim3 grid(IMG_W / TX, IMG_H / STRIP, NIMG);   // 16 x 8 x 16 = 2048 blocks
    const int nblocks = (IMG_W / TX) * (IMG_H / STRIP) * NIMG;
    const size_t needed = (size_t)nblocks * sizeof(float);

    if (ws_size >= needed) {
        ssim_strip_kernel<<<grid, 256, 0, stream>>>(img1, img2, partial, 0);
        ssim_reduce_kernel<<<1, 256, 0, stream>>>(partial, nblocks, out);
    } else {
        hipMemsetAsync(d_ws, 0, sizeof(float), stream);
        ssim_strip_kernel<<<grid, 256, 0, stream>>>(img1, img2, partial, 1);
        ssim_reduce_kernel<<<1, 256, 0, stream>>>(partial, 1, out);
    }
}

// Round 19
// 70.506 us; speedup vs baseline: 1.1178x; 1.1178x over previous
//
#include <hip/hip_runtime.h>
#include <hip/hip_fp16.h>

#define IMG_H 1024
#define IMG_W 1024
#define NIMG  16
#define RAD   5
#define KW    11
#define TX    64              // block tile width (cols); 16 per wave
#define WTX   16              // cols per wave
#define STRIP 128             // tile height (rows per block)
#define ASTEP 16              // h-blur rows per A step
#define BSTEP 32              // output rows per B step
#define HBROWS (STRIP + 2*RAD)   // 138 h-blurred rows per strip
#define RING  48              // ring rows per wave
#define WPAD  20              // halfs per hb ring row (16 + 4 pad)
#define NQ    4               // ring quantities: x, y, xx+yy, xy
#define NPIX  (NIMG * IMG_H * IMG_W)

// Gaussian(sigma=1.5, 11 taps), normalized fp32 — matches reference window.
__device__ __forceinline__ float gw(int k) {
    constexpr float G[KW] = {
        0.00102838f, 0.00759876f, 0.03600077f, 0.10936070f, 0.21300554f,
        0.26601173f,
        0.21300554f, 0.10936070f, 0.03600077f, 0.00759876f, 0.00102838f};
    return G[k];
}

__device__ __forceinline__ unsigned h2u(__half2 v) {
    union { __half2 h; unsigned u; } c; c.h = v; return c.u;
}
__device__ __forceinline__ __half2 u2h(unsigned v) {
    union { unsigned u; __half2 h; } c; c.u = v; return c.h;
}
// halfs (w[idx], w[idx+1]) from packed word array; odd idx = v_alignbit.
__device__ __forceinline__ __half2 hsel(const unsigned* hw, int idx) {
    unsigned r;
    if (idx & 1) r = (hw[idx >> 1] >> 16) | (hw[(idx >> 1) + 1] << 16);
    else         r = hw[idx >> 1];
    return u2h(r);
}

// R17 (67.7us: wave-private rings, barrier-free) + hb bank swizzle:
// un-swizzled, lanes (lr, lr+8) read rows r, r+16 -> word delta 160 = 0
// mod 32 -> same-bank serialization on EVERY B-read (7.4M conflict cyc).
// Fix: slot' = slot ^ ((row>>4)&1), applied on BOTH write and read sides
// (rule #21). Verified: 16 lr-lanes x fixed slot now hit 16 distinct banks.
__global__ __launch_bounds__(256, 8) void ssim_strip_kernel(
        const float* __restrict__ img1, const float* __restrict__ img2,
        float* __restrict__ partial, int atomic_mode) {
    __shared__ __align__(16) __half hb[4][NQ][RING][WPAD];   // 30,720 B
    __shared__ float wsum[4];

    const int t = threadIdx.x;
    const int wid = t >> 6;
    const int lane = t & 63;
    const int tile_y = blockIdx.y * STRIP;
    const int wx = blockIdx.x * TX + wid * WTX;   // wave's first output col
    const size_t img_off = (size_t)blockIdx.z * (IMG_H * IMG_W);
    const float* p1 = img1 + img_off;
    const float* p2 = img2 + img_off;

    const bool x_ok = (wx >= 8) && (wx + 24 <= IMG_W);

    // Phase A step a: h-blur halo rows h = 16a + (lane>>2) into the wave's
    // ring slot h%48, col group g4 = lane&3 (4 cols each).
    auto phaseA = [&](int a) {
        const int lr = lane >> 2;
        const int g4 = lane & 3;
        const int h = ASTEP * a + lr;
        if (h >= HBROWS) return;
        int rr = h;
        if (rr >= 96) rr -= 96;
        else if (rr >= RING) rr -= RING;
        const int gr = tile_y + h - RAD;
        const int gc0 = wx + g4 * 4 - 8;
        const bool row_ok = (tile_y + ASTEP * a - RAD >= 0) &&
                            (tile_y + ASTEP * a + ASTEP - 1 - RAD < IMG_H);
        unsigned hwx[10], hwy[10];
        if (x_ok && row_ok) {
            const size_t base = (size_t)gr * IMG_W + gc0;
#pragma unroll
            for (int w = 0; w < 5; ++w) {
                const float4 xa = *reinterpret_cast<const float4*>(p1 + base + 4 * w);
                const float4 ya = *reinterpret_cast<const float4*>(p2 + base + 4 * w);
                hwx[2 * w]     = h2u(__floats2half2_rn(xa.x, xa.y));
                hwx[2 * w + 1] = h2u(__floats2half2_rn(xa.z, xa.w));
                hwy[2 * w]     = h2u(__floats2half2_rn(ya.x, ya.y));
                hwy[2 * w + 1] = h2u(__floats2half2_rn(ya.z, ya.w));
            }
        } else {
            const bool rowok = ((unsigned)gr < (unsigned)IMG_H);
            const float* row1 = p1 + (size_t)gr * IMG_W;
            const float* row2 = p2 + (size_t)gr * IMG_W;
#pragma unroll
            for (int w = 0; w < 5; ++w) {
                const int gc = gc0 + 4 * w;
                float4 xa = make_float4(0.f, 0.f, 0.f, 0.f);
                float4 ya = make_float4(0.f, 0.f, 0.f, 0.f);
                if (rowok) {
                    if (gc >= 0 && gc <= IMG_W - 4) {
                        xa = *reinterpret_cast<const float4*>(row1 + gc);
                        ya = *reinterpret_cast<const float4*>(row2 + gc);
                    } else if (gc > -4 && gc < IMG_W) {
                        float* ex = &xa.x;
                        float* ey = &ya.x;
#pragma unroll
                        for (int j = 0; j < 4; ++j) {
                            int g = gc + j;
                            if ((unsigned)g < (unsigned)IMG_W) {
                                ex[j] = row1[g];
                                ey[j] = row2[g];
                            }
                        }
                    }
                }
                hwx[2 * w]     = h2u(__floats2half2_rn(xa.x, xa.y));
                hwx[2 * w + 1] = h2u(__floats2half2_rn(xa.z, xa.w));
                hwy[2 * w]     = h2u(__floats2half2_rn(ya.x, ya.y));
                hwy[2 * w + 1] = h2u(__floats2half2_rn(ya.z, ya.w));
            }
        }
        __half2 A0[2], A1[2], A2[2], A3[2];
#pragma unroll
        for (int p = 0; p < 2; ++p)
            A0[p] = A1[p] = A2[p] = A3[p] = u2h(0u);
#pragma unroll
        for (int k = 0; k < KW; ++k) {
            const __half2 g2 = __float2half2_rn(gw(k));
#pragma unroll
            for (int p = 0; p < 2; ++p) {
                const int idx = 2 * p + 3 + k;
                const __half2 X = hsel(hwx, idx);
                const __half2 Y = hsel(hwy, idx);
                A0[p] = __hfma2(g2, X, A0[p]);
                A1[p] = __hfma2(g2, Y, A1[p]);
                const __half2 gx = __hmul2(g2, X);
                const __half2 gy = __hmul2(g2, Y);
                A2[p] = __hfma2(gx, X, A2[p]);
                A2[p] = __hfma2(gy, Y, A2[p]);
                A3[p] = __hfma2(gx, Y, A3[p]);
            }
        }
        const int gsw = (g4 ^ ((rr >> 4) & 1)) * 4;   // bank swizzle (write)
        *reinterpret_cast<uint2*>(&hb[wid][0][rr][gsw]) = make_uint2(h2u(A0[0]), h2u(A0[1]));
        *reinterpret_cast<uint2*>(&hb[wid][1][rr][gsw]) = make_uint2(h2u(A1[0]), h2u(A1[1]));
        *reinterpret_cast<uint2*>(&hb[wid][2][rr][gsw]) = make_uint2(h2u(A2[0]), h2u(A2[1]));
        *reinterpret_cast<uint2*>(&hb[wid][3][rr][gsw]) = make_uint2(h2u(A3[0]), h2u(A3[1]));
    };

    float lsum = 0.f;

    // Phase B step s: v-blur + SSIM for output rows 32s..32s+31.
    // lane: 4 cols (slot = lane&3) x 2 rows (r2 = (lane>>2)*2).
    auto phaseB = [&](int s) {
        __half2 gh2[KW];
#pragma unroll
        for (int k = 0; k < KW; ++k) gh2[k] = __float2half2_rn(gw(k));

        const int rbase = (BSTEP * s) % RING;   // 0,32,16,0
        const int slot = lane & 3;
        const int r2 = (lane >> 2) * 2;
        __half2 acc[NQ][2][2];
#pragma unroll
        for (int q = 0; q < NQ; ++q)
#pragma unroll
            for (int rl = 0; rl < 2; ++rl)
#pragma unroll
                for (int cp = 0; cp < 2; ++cp)
                    acc[q][rl][cp] = u2h(0u);

#pragma unroll
        for (int q = 0; q < NQ; ++q) {
#pragma unroll
            for (int k = 0; k < KW + 1; ++k) {
                int r = rbase + r2 + k;
                if (r >= RING) r -= RING;
                const int ssw = (slot ^ ((r >> 4) & 1)) * 4;  // swizzle (read)
                const uint2 rv =
                    *reinterpret_cast<const uint2*>(&hb[wid][q][r][ssw]);
                __half2 h0 = u2h(rv.x);
                __half2 h1 = u2h(rv.y);
                if (k < KW) {
                    acc[q][0][0] = __hfma2(gh2[k], h0, acc[q][0][0]);
                    acc[q][0][1] = __hfma2(gh2[k], h1, acc[q][0][1]);
                }
                if (k > 0) {
                    acc[q][1][0] = __hfma2(gh2[k - 1], h0, acc[q][1][0]);
                    acc[q][1][1] = __hfma2(gh2[k - 1], h1, acc[q][1][1]);
                }
            }
        }

        const float C1 = 0.0001f;
        const float C2 = 0.0009f;
#pragma unroll
        for (int rl = 0; rl < 2; ++rl) {
#pragma unroll
            for (int cp = 0; cp < 2; ++cp) {
                float2 m1p = __half22float2(acc[0][rl][cp]);
                float2 m2p = __half22float2(acc[1][rl][cp]);
                float2 Sp  = __half22float2(acc[2][rl][cp]);   // blur(xx+yy)
                float2 Pp  = __half22float2(acc[3][rl][cp]);   // blur(xy)
#pragma unroll
                for (int e = 0; e < 2; ++e) {
                    float m1 = e ? m1p.y : m1p.x;
                    float m2 = e ? m2p.y : m2p.x;
                    float S  = e ? Sp.y  : Sp.x;
                    float P  = e ? Pp.y  : Pp.x;
                    float m1s = m1 * m1;
                    float m2s = m2 * m2;
                    float m12 = m1 * m2;
                    float sigsum = S - m1s - m2s;
                    float sig12  = P - m12;
                    float num = (2.f * m12 + C1) * (2.f * sig12 + C2);
                    float den = (m1s + m2s + C1) * (sigsum + C2);
                    lsum = fmaf(num, __builtin_amdgcn_rcpf(den), lsum);
                }
            }
        }
    };

    // Barrier-free per-wave schedule (ring safety identical to R17:
    // same RING/ASTEP/BSTEP stepping, enforced by wave program order).
#pragma unroll 1
    for (int a = 0; a < 9; ++a) {
        phaseA(a);
        if (a >= 2 && ((a & 1) == 0)) {
            phaseB((a - 2) >> 1);
        }
    }

    // ---- block reduction (single barrier of the kernel) ----
#pragma unroll
    for (int off = 32; off > 0; off >>= 1)
        lsum += __shfl_down(lsum, off, 64);
    if (lane == 0) wsum[wid] = lsum;
    __syncthreads();
    if (t == 0) {
        float s = wsum[0] + wsum[1] + wsum[2] + wsum[3];
        if (atomic_mode) {
            atomicAdd(partial, s);
        } else {
            int bid = (blockIdx.z * gridDim.y + blockIdx.y) * gridDim.x + blockIdx.x;
            partial[bid] = s;
        }
    }
}

__global__ __launch_bounds__(256) void ssim_reduce_kernel(
        const float* __restrict__ partial, int n, float* __restrict__ out) {
    float s = 0.f;
    for (int i = threadIdx.x; i < n; i += 256) s += partial[i];
#pragma unroll
    for (int off = 32; off > 0; off >>= 1)
        s += __shfl_down(s, off, 64);
    __shared__ float ws[4];
    if ((threadIdx.x & 63) == 0) ws[threadIdx.x >> 6] = s;
    __syncthreads();
    if (threadIdx.x == 0) {
        float tot = ws[0] + ws[1] + ws[2] + ws[3];
        out[0] = 1.f - tot / (float)NPIX;
    }
}

extern "C" void kernel_launch(void* const* d_in, const int* in_sizes, int n_in,
                              void* d_out, int out_size, void* d_ws, size_t ws_size,
                              hipStream_t stream) {
    const float* img1 = (const float*)d_in[0];
    const float* img2 = (const float*)d_in[1];
    float* out = (float*)d_out;
    float* partial = (float*)d_ws;

    dim3 grid(IMG_W / TX, IMG_H / STRIP, NIMG);   // 16 x 8 x 16 = 2048 blocks
    const int nblocks = (IMG_W / TX) * (IMG_H / STRIP) * NIMG;
    const size_t needed = (size_t)nblocks * sizeof(float);

    if (ws_size >= needed) {
        ssim_strip_kernel<<<grid, 256, 0, stream>>>(img1, img2, partial, 0);
        ssim_reduce_kernel<<<1, 256, 0, stream>>>(partial, nblocks, out);
    } else {
        hipMemsetAsync(d_ws, 0, sizeof(float), stream);
        ssim_strip_kernel<<<grid, 256, 0, stream>>>(img1, img2, partial, 1);
        ssim_reduce_kernel<<<1, 256, 0, stream>>>(partial, 1, out);
    }
}

// Round 20
// 69.876 us; speedup vs baseline: 1.1278x; 1.0090x over previous
//
#include <hip/hip_runtime.h>
#include <hip/hip_fp16.h>

#define IMG_H 1024
#define IMG_W 1024
#define NIMG  16
#define RAD   5
#define KW    11
#define TX    64              // block tile width (cols); 16 per wave
#define WTX   16              // cols per wave
#define STRIP 128             // tile height (rows per block)
#define ASTEP 16              // h-blur rows per A step
#define BSTEP 32              // output rows per B step
#define HBROWS (STRIP + 2*RAD)   // 138 h-blurred rows per strip
#define RING  48              // ring rows per wave
#define WPAD  20              // halfs per hb ring row (16 + 4 pad)
#define NQ    4               // ring quantities: x, y, xx+yy, xy
#define NPIX  (NIMG * IMG_H * IMG_W)

// Gaussian(sigma=1.5, 11 taps), normalized fp32 — matches reference window.
__device__ __forceinline__ float gw(int k) {
    constexpr float G[KW] = {
        0.00102838f, 0.00759876f, 0.03600077f, 0.10936070f, 0.21300554f,
        0.26601173f,
        0.21300554f, 0.10936070f, 0.03600077f, 0.00759876f, 0.00102838f};
    return G[k];
}

__device__ __forceinline__ unsigned h2u(__half2 v) {
    union { __half2 h; unsigned u; } c; c.h = v; return c.u;
}
__device__ __forceinline__ __half2 u2h(unsigned v) {
    union { unsigned u; __half2 h; } c; c.u = v; return c.h;
}
// halfs (w[idx], w[idx+1]) from packed word array; odd idx = v_alignbit.
__device__ __forceinline__ __half2 hsel(const unsigned* hw, int idx) {
    unsigned r;
    if (idx & 1) r = (hw[idx >> 1] >> 16) | (hw[(idx >> 1) + 1] << 16);
    else         r = hw[idx >> 1];
    return u2h(r);
}

// R17 (67.7us: wave-private rings, barrier-free) + taller B micro-tile:
// thread covers 4 rows x 2 cols (was 2x4) -> per quantity 14 b32 row-reads
// serve 4 output words (was 24 words for 4) — LDS read bytes −42%, and the
// b32 pattern (bank = 8*(lr&3)+slot) is a free 2-way. R19's b64 "conflicts"
// were the inherent 4-cycle/512B service floor — identical counter value
// under swizzle proved them layout-invariant; swizzle reverted.
__global__ __launch_bounds__(256, 8) void ssim_strip_kernel(
        const float* __restrict__ img1, const float* __restrict__ img2,
        float* __restrict__ partial, int atomic_mode) {
    __shared__ __align__(16) __half hb[4][NQ][RING][WPAD];   // 30,720 B
    __shared__ float wsum[4];

    const int t = threadIdx.x;
    const int wid = t >> 6;
    const int lane = t & 63;
    const int tile_y = blockIdx.y * STRIP;
    const int wx = blockIdx.x * TX + wid * WTX;   // wave's first output col
    const size_t img_off = (size_t)blockIdx.z * (IMG_H * IMG_W);
    const float* p1 = img1 + img_off;
    const float* p2 = img2 + img_off;

    const bool x_ok = (wx >= 8) && (wx + 24 <= IMG_W);

    // Phase A step a: h-blur halo rows h = 16a + (lane>>2) into the wave's
    // ring slot h%48, col group g4 = lane&3 (4 cols each).
    auto phaseA = [&](int a) {
        const int lr = lane >> 2;
        const int g4 = lane & 3;
        const int h = ASTEP * a + lr;
        if (h >= HBROWS) return;
        int rr = h;
        if (rr >= 96) rr -= 96;
        else if (rr >= RING) rr -= RING;
        const int gr = tile_y + h - RAD;
        const int gc0 = wx + g4 * 4 - 8;
        const bool row_ok = (tile_y + ASTEP * a - RAD >= 0) &&
                            (tile_y + ASTEP * a + ASTEP - 1 - RAD < IMG_H);
        unsigned hwx[10], hwy[10];
        if (x_ok && row_ok) {
            const size_t base = (size_t)gr * IMG_W + gc0;
#pragma unroll
            for (int w = 0; w < 5; ++w) {
                const float4 xa = *reinterpret_cast<const float4*>(p1 + base + 4 * w);
                const float4 ya = *reinterpret_cast<const float4*>(p2 + base + 4 * w);
                hwx[2 * w]     = h2u(__floats2half2_rn(xa.x, xa.y));
                hwx[2 * w + 1] = h2u(__floats2half2_rn(xa.z, xa.w));
                hwy[2 * w]     = h2u(__floats2half2_rn(ya.x, ya.y));
                hwy[2 * w + 1] = h2u(__floats2half2_rn(ya.z, ya.w));
            }
        } else {
            const bool rowok = ((unsigned)gr < (unsigned)IMG_H);
            const float* row1 = p1 + (size_t)gr * IMG_W;
            const float* row2 = p2 + (size_t)gr * IMG_W;
#pragma unroll
            for (int w = 0; w < 5; ++w) {
                const int gc = gc0 + 4 * w;
                float4 xa = make_float4(0.f, 0.f, 0.f, 0.f);
                float4 ya = make_float4(0.f, 0.f, 0.f, 0.f);
                if (rowok) {
                    if (gc >= 0 && gc <= IMG_W - 4) {
                        xa = *reinterpret_cast<const float4*>(row1 + gc);
                        ya = *reinterpret_cast<const float4*>(row2 + gc);
                    } else if (gc > -4 && gc < IMG_W) {
                        float* ex = &xa.x;
                        float* ey = &ya.x;
#pragma unroll
                        for (int j = 0; j < 4; ++j) {
                            int g = gc + j;
                            if ((unsigned)g < (unsigned)IMG_W) {
                                ex[j] = row1[g];
                                ey[j] = row2[g];
                            }
                        }
                    }
                }
                hwx[2 * w]     = h2u(__floats2half2_rn(xa.x, xa.y));
                hwx[2 * w + 1] = h2u(__floats2half2_rn(xa.z, xa.w));
                hwy[2 * w]     = h2u(__floats2half2_rn(ya.x, ya.y));
                hwy[2 * w + 1] = h2u(__floats2half2_rn(ya.z, ya.w));
            }
        }
        __half2 A0[2], A1[2], A2[2], A3[2];
#pragma unroll
        for (int p = 0; p < 2; ++p)
            A0[p] = A1[p] = A2[p] = A3[p] = u2h(0u);
#pragma unroll
        for (int k = 0; k < KW; ++k) {
            const __half2 g2 = __float2half2_rn(gw(k));
#pragma unroll
            for (int p = 0; p < 2; ++p) {
                const int idx = 2 * p + 3 + k;
                const __half2 X = hsel(hwx, idx);
                const __half2 Y = hsel(hwy, idx);
                A0[p] = __hfma2(g2, X, A0[p]);
                A1[p] = __hfma2(g2, Y, A1[p]);
                const __half2 gx = __hmul2(g2, X);
                const __half2 gy = __hmul2(g2, Y);
                A2[p] = __hfma2(gx, X, A2[p]);
                A2[p] = __hfma2(gy, Y, A2[p]);
                A3[p] = __hfma2(gx, Y, A3[p]);
            }
        }
        *reinterpret_cast<uint2*>(&hb[wid][0][rr][g4 * 4]) = make_uint2(h2u(A0[0]), h2u(A0[1]));
        *reinterpret_cast<uint2*>(&hb[wid][1][rr][g4 * 4]) = make_uint2(h2u(A1[0]), h2u(A1[1]));
        *reinterpret_cast<uint2*>(&hb[wid][2][rr][g4 * 4]) = make_uint2(h2u(A2[0]), h2u(A2[1]));
        *reinterpret_cast<uint2*>(&hb[wid][3][rr][g4 * 4]) = make_uint2(h2u(A3[0]), h2u(A3[1]));
    };

    float lsum = 0.f;

    // Phase B step s: v-blur + SSIM for output rows 32s..32s+31.
    // lane: 2 cols (slot = lane&7 -> word) x 4 rows (r4 = (lane>>3)*4).
    // Per quantity: 14 b32 reads (rows r4..r4+13) feed 4 row-accumulators.
    auto phaseB = [&](int s) {
        __half2 gh2[KW];
#pragma unroll
        for (int k = 0; k < KW; ++k) gh2[k] = __float2half2_rn(gw(k));

        const int rbase = (BSTEP * s) % RING;   // 0,32,16,0
        const int slot = lane & 7;              // word index (2 cols)
        const int r4 = (lane >> 3) * 4;         // 0,4,...,28
        __half2 acc[NQ][4];
#pragma unroll
        for (int q = 0; q < NQ; ++q)
#pragma unroll
            for (int j = 0; j < 4; ++j)
                acc[q][j] = u2h(0u);

#pragma unroll
        for (int q = 0; q < NQ; ++q) {
#pragma unroll
            for (int k = 0; k < KW + 3; ++k) {   // 14 rows: r4+k, k=0..13
                int r = rbase + r4 + k;          // <= 32+28+13 = 73
                if (r >= RING) r -= RING;
                const __half2 hv = u2h(
                    *reinterpret_cast<const unsigned*>(&hb[wid][q][r][slot * 2]));
#pragma unroll
                for (int j = 0; j < 4; ++j) {
                    const int kk = k - j;
                    if (kk >= 0 && kk < KW)
                        acc[q][j] = __hfma2(gh2[kk], hv, acc[q][j]);
                }
            }
        }

        const float C1 = 0.0001f;
        const float C2 = 0.0009f;
#pragma unroll
        for (int j = 0; j < 4; ++j) {
            float2 m1p = __half22float2(acc[0][j]);
            float2 m2p = __half22float2(acc[1][j]);
            float2 Sp  = __half22float2(acc[2][j]);   // blur(xx+yy)
            float2 Pp  = __half22float2(acc[3][j]);   // blur(xy)
#pragma unroll
            for (int e = 0; e < 2; ++e) {
                float m1 = e ? m1p.y : m1p.x;
                float m2 = e ? m2p.y : m2p.x;
                float S  = e ? Sp.y  : Sp.x;
                float P  = e ? Pp.y  : Pp.x;
                float m1s = m1 * m1;
                float m2s = m2 * m2;
                float m12 = m1 * m2;
                float sigsum = S - m1s - m2s;
                float sig12  = P - m12;
                float num = (2.f * m12 + C1) * (2.f * sig12 + C2);
                float den = (m1s + m2s + C1) * (sigsum + C2);
                lsum = fmaf(num, __builtin_amdgcn_rcpf(den), lsum);
            }
        }
    };

    // Barrier-free per-wave schedule (ring safety identical to R17:
    // same RING/ASTEP/BSTEP stepping, enforced by wave program order).
#pragma unroll 1
    for (int a = 0; a < 9; ++a) {
        phaseA(a);
        if (a >= 2 && ((a & 1) == 0)) {
            phaseB((a - 2) >> 1);
        }
    }

    // ---- block reduction (single barrier of the kernel) ----
#pragma unroll
    for (int off = 32; off > 0; off >>= 1)
        lsum += __shfl_down(lsum, off, 64);
    if (lane == 0) wsum[wid] = lsum;
    __syncthreads();
    if (t == 0) {
        float s = wsum[0] + wsum[1] + wsum[2] + wsum[3];
        if (atomic_mode) {
            atomicAdd(partial, s);
        } else {
            int bid = (blockIdx.z * gridDim.y + blockIdx.y) * gridDim.x + blockIdx.x;
            partial[bid] = s;
        }
    }
}

__global__ __launch_bounds__(256) void ssim_reduce_kernel(
        const float* __restrict__ partial, int n, float* __restrict__ out) {
    float s = 0.f;
    for (int i = threadIdx.x; i < n; i += 256) s += partial[i];
#pragma unroll
    for (int off = 32; off > 0; off >>= 1)
        s += __shfl_down(s, off, 64);
    __shared__ float ws[4];
    if ((threadIdx.x & 63) == 0) ws[threadIdx.x >> 6] = s;
    __syncthreads();
    if (threadIdx.x == 0) {
        float tot = ws[0] + ws[1] + ws[2] + ws[3];
        out[0] = 1.f - tot / (float)NPIX;
    }
}

extern "C" void kernel_launch(void* const* d_in, const int* in_sizes, int n_in,
                              void* d_out, int out_size, void* d_ws, size_t ws_size,
                              hipStream_t stream) {
    const float* img1 = (const float*)d_in[0];
    const float* img2 = (const float*)d_in[1];
    float* out = (float*)d_out;
    float* partial = (float*)d_ws;

    dim3 grid(IMG_W / TX, IMG_H / STRIP, NIMG);   // 16 x 8 x 16 = 2048 blocks
    const int nblocks = (IMG_W / TX) * (IMG_H / STRIP) * NIMG;
    const size_t needed = (size_t)nblocks * sizeof(float);

    if (ws_size >= needed) {
        ssim_strip_kernel<<<grid, 256, 0, stream>>>(img1, img2, partial, 0);
        ssim_reduce_kernel<<<1, 256, 0, stream>>>(partial, nblocks, out);
    } else {
        hipMemsetAsync(d_ws, 0, sizeof(float), stream);
        ssim_strip_kernel<<<grid, 256, 0, stream>>>(img1, img2, partial, 1);
        ssim_reduce_kernel<<<1, 256, 0, stream>>>(partial, 1, out);
    }
}

// Round 21
// 68.905 us; speedup vs baseline: 1.1437x; 1.0141x over previous
//
#include <hip/hip_runtime.h>
#include <hip/hip_fp16.h>

#define IMG_H 1024
#define IMG_W 1024
#define NIMG  16
#define RAD   5
#define KW    11
#define TX    64              // block tile width (cols); 16 per wave
#define WTX   16              // cols per wave
#define STRIP 128             // tile height (rows per block)
#define ASTEP 16              // h-blur rows per A step
#define BSTEP 16              // output rows per B step
#define HBROWS (STRIP + 2*RAD)   // 138 h-blurred rows per strip
#define RING  32              // ring rows per wave (pow2: slot = h & 31)
#define WPAD  20              // halfs per hb ring row (16 + 4 pad)
#define NQ    4               // ring quantities: x, y, xx+yy, xy
#define NPIX  (NIMG * IMG_H * IMG_W)

// Gaussian(sigma=1.5, 11 taps), normalized fp32 — matches reference window.
__device__ __forceinline__ float gw(int k) {
    constexpr float G[KW] = {
        0.00102838f, 0.00759876f, 0.03600077f, 0.10936070f, 0.21300554f,
        0.26601173f,
        0.21300554f, 0.10936070f, 0.03600077f, 0.00759876f, 0.00102838f};
    return G[k];
}

__device__ __forceinline__ unsigned h2u(__half2 v) {
    union { __half2 h; unsigned u; } c; c.h = v; return c.u;
}
__device__ __forceinline__ __half2 u2h(unsigned v) {
    union { unsigned u; __half2 h; } c; c.u = v; return c.h;
}
// halfs (w[idx], w[idx+1]) from packed word array; odd idx = v_alignbit.
__device__ __forceinline__ __half2 hsel(const unsigned* hw, int idx) {
    unsigned r;
    if (idx & 1) r = (hw[idx >> 1] >> 16) | (hw[(idx >> 1) + 1] << 16);
    else         r = hw[idx >> 1];
    return u2h(r);
}

// R20 + ring halving for occupancy: R20 proved LDS service is off the
// critical path (conflicts 7.4M->1.1M, time flat) — the kernel is
// VALU+latency bound at only ~3 waves/SIMD resident. RING 48->32 and
// BSTEP 32->16 cut LDS to 20,480 B -> 7 blocks/CU (28 waves, 7/SIMD);
// VGPR=48 already permits 8 waves/SIMD. Schedule A0 A1 | B0 A2 | ... | B7;
// ring safety by wave program order (B(s) reads h16s..16s+25 all live;
// A(s+2) overwrites only rows last read by B(s); B7 sees A8's h128-137).
__global__ __launch_bounds__(256, 8) void ssim_strip_kernel(
        const float* __restrict__ img1, const float* __restrict__ img2,
        float* __restrict__ partial, int atomic_mode) {
    __shared__ __align__(16) __half hb[4][NQ][RING][WPAD];   // 20,480 B
    __shared__ float wsum[4];

    const int t = threadIdx.x;
    const int wid = t >> 6;
    const int lane = t & 63;
    const int tile_y = blockIdx.y * STRIP;
    const int wx = blockIdx.x * TX + wid * WTX;   // wave's first output col
    const size_t img_off = (size_t)blockIdx.z * (IMG_H * IMG_W);
    const float* p1 = img1 + img_off;
    const float* p2 = img2 + img_off;

    const bool x_ok = (wx >= 8) && (wx + 24 <= IMG_W);

    // Phase A step a: h-blur halo rows h = 16a + (lane>>2) into the wave's
    // ring slot h&31, col group g4 = lane&3 (4 cols each).
    auto phaseA = [&](int a) {
        const int lr = lane >> 2;
        const int g4 = lane & 3;
        const int h = ASTEP * a + lr;
        if (h >= HBROWS) return;
        const int rr = h & (RING - 1);
        const int gr = tile_y + h - RAD;
        const int gc0 = wx + g4 * 4 - 8;
        const bool row_ok = (tile_y + ASTEP * a - RAD >= 0) &&
                            (tile_y + ASTEP * a + ASTEP - 1 - RAD < IMG_H);
        unsigned hwx[10], hwy[10];
        if (x_ok && row_ok) {
            const size_t base = (size_t)gr * IMG_W + gc0;
#pragma unroll
            for (int w = 0; w < 5; ++w) {
                const float4 xa = *reinterpret_cast<const float4*>(p1 + base + 4 * w);
                const float4 ya = *reinterpret_cast<const float4*>(p2 + base + 4 * w);
                hwx[2 * w]     = h2u(__floats2half2_rn(xa.x, xa.y));
                hwx[2 * w + 1] = h2u(__floats2half2_rn(xa.z, xa.w));
                hwy[2 * w]     = h2u(__floats2half2_rn(ya.x, ya.y));
                hwy[2 * w + 1] = h2u(__floats2half2_rn(ya.z, ya.w));
            }
        } else {
            const bool rowok = ((unsigned)gr < (unsigned)IMG_H);
            const float* row1 = p1 + (size_t)gr * IMG_W;
            const float* row2 = p2 + (size_t)gr * IMG_W;
#pragma unroll
            for (int w = 0; w < 5; ++w) {
                const int gc = gc0 + 4 * w;
                float4 xa = make_float4(0.f, 0.f, 0.f, 0.f);
                float4 ya = make_float4(0.f, 0.f, 0.f, 0.f);
                if (rowok) {
                    if (gc >= 0 && gc <= IMG_W - 4) {
                        xa = *reinterpret_cast<const float4*>(row1 + gc);
                        ya = *reinterpret_cast<const float4*>(row2 + gc);
                    } else if (gc > -4 && gc < IMG_W) {
                        float* ex = &xa.x;
                        float* ey = &ya.x;
#pragma unroll
                        for (int j = 0; j < 4; ++j) {
                            int g = gc + j;
                            if ((unsigned)g < (unsigned)IMG_W) {
                                ex[j] = row1[g];
                                ey[j] = row2[g];
                            }
                        }
                    }
                }
                hwx[2 * w]     = h2u(__floats2half2_rn(xa.x, xa.y));
                hwx[2 * w + 1] = h2u(__floats2half2_rn(xa.z, xa.w));
                hwy[2 * w]     = h2u(__floats2half2_rn(ya.x, ya.y));
                hwy[2 * w + 1] = h2u(__floats2half2_rn(ya.z, ya.w));
            }
        }
        __half2 A0[2], A1[2], A2[2], A3[2];
#pragma unroll
        for (int p = 0; p < 2; ++p)
            A0[p] = A1[p] = A2[p] = A3[p] = u2h(0u);
#pragma unroll
        for (int k = 0; k < KW; ++k) {
            const __half2 g2 = __float2half2_rn(gw(k));
#pragma unroll
            for (int p = 0; p < 2; ++p) {
                const int idx = 2 * p + 3 + k;
                const __half2 X = hsel(hwx, idx);
                const __half2 Y = hsel(hwy, idx);
                A0[p] = __hfma2(g2, X, A0[p]);
                A1[p] = __hfma2(g2, Y, A1[p]);
                const __half2 gx = __hmul2(g2, X);
                const __half2 gy = __hmul2(g2, Y);
                A2[p] = __hfma2(gx, X, A2[p]);
                A2[p] = __hfma2(gy, Y, A2[p]);
                A3[p] = __hfma2(gx, Y, A3[p]);
            }
        }
        *reinterpret_cast<uint2*>(&hb[wid][0][rr][g4 * 4]) = make_uint2(h2u(A0[0]), h2u(A0[1]));
        *reinterpret_cast<uint2*>(&hb[wid][1][rr][g4 * 4]) = make_uint2(h2u(A1[0]), h2u(A1[1]));
        *reinterpret_cast<uint2*>(&hb[wid][2][rr][g4 * 4]) = make_uint2(h2u(A2[0]), h2u(A2[1]));
        *reinterpret_cast<uint2*>(&hb[wid][3][rr][g4 * 4]) = make_uint2(h2u(A3[0]), h2u(A3[1]));
    };

    float lsum = 0.f;

    // Phase B step s: v-blur + SSIM for output rows 16s..16s+15.
    // lane: 2 cols (slot = lane&7 -> word) x 2 rows (r2 = (lane>>3)*2).
    // Per quantity: 12 b32 reads (rows r2..r2+11) feed 2 row-accumulators.
    // Bank: word = 20*rg + 10*k + slot; per k the 64 lanes land exactly
    // 2-per-bank (bases {0,20,8,28,16,4,24,12} + slot 0..7) — free 2-way.
    auto phaseB = [&](int s) {
        __half2 gh2[KW];
#pragma unroll
        for (int k = 0; k < KW; ++k) gh2[k] = __float2half2_rn(gw(k));

        const int rbase = (BSTEP * s) & (RING - 1);   // 0,16 alternating
        const int slot = lane & 7;                    // word index (2 cols)
        const int r2 = (lane >> 3) * 2;               // 0,2,...,14
        __half2 acc[NQ][2];
#pragma unroll
        for (int q = 0; q < NQ; ++q)
#pragma unroll
            for (int j = 0; j < 2; ++j)
                acc[q][j] = u2h(0u);

#pragma unroll
        for (int q = 0; q < NQ; ++q) {
#pragma unroll
            for (int k = 0; k < KW + 1; ++k) {   // 12 rows: r2+k, k=0..11
                const int r = (rbase + r2 + k) & (RING - 1);
                const __half2 hv = u2h(
                    *reinterpret_cast<const unsigned*>(&hb[wid][q][r][slot * 2]));
#pragma unroll
                for (int j = 0; j < 2; ++j) {
                    const int kk = k - j;
                    if (kk >= 0 && kk < KW)
                        acc[q][j] = __hfma2(gh2[kk], hv, acc[q][j]);
                }
            }
        }

        const float C1 = 0.0001f;
        const float C2 = 0.0009f;
#pragma unroll
        for (int j = 0; j < 2; ++j) {
            float2 m1p = __half22float2(acc[0][j]);
            float2 m2p = __half22float2(acc[1][j]);
            float2 Sp  = __half22float2(acc[2][j]);   // blur(xx+yy)
            float2 Pp  = __half22float2(acc[3][j]);   // blur(xy)
#pragma unroll
            for (int e = 0; e < 2; ++e) {
                float m1 = e ? m1p.y : m1p.x;
                float m2 = e ? m2p.y : m2p.x;
                float S  = e ? Sp.y  : Sp.x;
                float P  = e ? Pp.y  : Pp.x;
                float m1s = m1 * m1;
                float m2s = m2 * m2;
                float m12 = m1 * m2;
                float sigsum = S - m1s - m2s;
                float sig12  = P - m12;
                float num = (2.f * m12 + C1) * (2.f * sig12 + C2);
                float den = (m1s + m2s + C1) * (sigsum + C2);
                lsum = fmaf(num, __builtin_amdgcn_rcpf(den), lsum);
            }
        }
    };

    // Barrier-free per-wave schedule: A0 A1 | B0 A2 | B1 A3 | ... | B7.
    phaseA(0);
    phaseA(1);
#pragma unroll 1
    for (int s = 0; s < 8; ++s) {
        phaseB(s);
        if (s + 2 <= 8) phaseA(s + 2);
    }

    // ---- block reduction (single barrier of the kernel) ----
#pragma unroll
    for (int off = 32; off > 0; off >>= 1)
        lsum += __shfl_down(lsum, off, 64);
    if (lane == 0) wsum[wid] = lsum;
    __syncthreads();
    if (t == 0) {
        float s = wsum[0] + wsum[1] + wsum[2] + wsum[3];
        if (atomic_mode) {
            atomicAdd(partial, s);
        } else {
            int bid = (blockIdx.z * gridDim.y + blockIdx.y) * gridDim.x + blockIdx.x;
            partial[bid] = s;
        }
    }
}

__global__ __launch_bounds__(256) void ssim_reduce_kernel(
        const float* __restrict__ partial, int n, float* __restrict__ out) {
    float s = 0.f;
    for (int i = threadIdx.x; i < n; i += 256) s += partial[i];
#pragma unroll
    for (int off = 32; off > 0; off >>= 1)
        s += __shfl_down(s, off, 64);
    __shared__ float ws[4];
    if ((threadIdx.x & 63) == 0) ws[threadIdx.x >> 6] = s;
    __syncthreads();
    if (threadIdx.x == 0) {
        float tot = ws[0] + ws[1] + ws[2] + ws[3];
        out[0] = 1.f - tot / (float)NPIX;
    }
}

extern "C" void kernel_launch(void* const* d_in, const int* in_sizes, int n_in,
                              void* d_out, int out_size, void* d_ws, size_t ws_size,
                              hipStream_t stream) {
    const float* img1 = (const float*)d_in[0];
    const float* img2 = (const float*)d_in[1];
    float* out = (float*)d_out;
    float* partial = (float*)d_ws;

    dim3 grid(IMG_W / TX, IMG_H / STRIP, NIMG);   // 16 x 8 x 16 = 2048 blocks
    const int nblocks = (IMG_W / TX) * (IMG_H / STRIP) * NIMG;
    const size_t needed = (size_t)nblocks * sizeof(float);

    if (ws_size >= needed) {
        ssim_strip_kernel<<<grid, 256, 0, stream>>>(img1, img2, partial, 0);
        ssim_reduce_kernel<<<1, 256, 0, stream>>>(partial, nblocks, out);
    } else {
        hipMemsetAsync(d_ws, 0, sizeof(float), stream);
        ssim_strip_kernel<<<grid, 256, 0, stream>>>(img1, img2, partial, 1);
        ssim_reduce_kernel<<<1, 256, 0, stream>>>(partial, 1, out);
    }
}